// Round 9
// baseline (226.827 us; speedup 1.0000x reference)
//
#include <hip/hip_runtime.h>

// ---------------------------------------------------------------------------
// Attention: y = softmax( (xWq^T)(xWk^T)^T / sqrt(128) ) (xWv^T)
// B=4, N=4096, H=OUT=128. fp32 I/O, bf16 MFMA compute.
//
// R9: abandon the 4-qt/wave experiment (spilled twice: allocator pins 128
// arch VGPRs regardless of waves_per_eu). Return to r6's spill-free
// 2-qt/wave loop, but:
//  - flash: 8 waves/block = 8 key-splits in-block (S=8, tree LDS combine,
//    no pbuf/norm). 4096 waves = 4/SIMD (r6 had 2) -> latency hiding.
//  - proj: wswz pre-kernel puts W into fragment layout once (QSCALE folded
//    into Wq); proj is barrier-free, W-frag loads are coalesced + L2-hot,
//    4 blocks/CU.
// ---------------------------------------------------------------------------

typedef __bf16 bf16;
typedef __attribute__((ext_vector_type(8))) __bf16 bf16x8;
typedef __attribute__((ext_vector_type(4))) float f32x4;

#define MFMA16(a, b, c) __builtin_amdgcn_mfma_f32_16x16x32_bf16(a, b, c, 0, 0, 0)

#if __has_builtin(__builtin_amdgcn_exp2f)
#define EXP2F(x) __builtin_amdgcn_exp2f(x)
#else
#define EXP2F(x) exp2f(x)
#endif

static constexpr int BATCH = 4;
static constexpr int N = 4096;
static constexpr int D = 128;
static constexpr int ROWS = BATCH * N;  // 16384
// fold 1/sqrt(128) and log2(e) into Wq so softmax is raw exp2
static constexpr float QSCALE = 0.088388347648318447f * 1.4426950408889634f;

__device__ inline bf16x8 ld8_f32_bf16(const float* __restrict__ p) {
    f32x4 a = *(const f32x4*)p;
    f32x4 b = *(const f32x4*)(p + 4);
    bf16x8 r;
    r[0] = (bf16)a[0]; r[1] = (bf16)a[1]; r[2] = (bf16)a[2]; r[3] = (bf16)a[3];
    r[4] = (bf16)b[0]; r[5] = (bf16)b[1]; r[6] = (bf16)b[2]; r[7] = (bf16)b[3];
    return r;
}

// Fragment layouts (16x16x32 bf16; lane = quad*16 + l16):
//  qf/kf: (tile,row,d) -> ((tile*4 + (d>>5))*64 + ((d&31)>>3)*16 + row)*8 + (d&7)
//  vf:    (o,key)      -> ((vg*8 + (o>>4))*64 + ((key&31)>>3)*16 + (o&15))*8 + (key&7)
//         with vg = batch*128 + (key_in_batch>>5)
//  wf:    3 x 16384 bf16; W[r][h] -> [(r>>4)*4+(h>>5)]*64 + ((h&31)>>3)*16+(r&15)],
//         j = h&7  (same mapping for A- and B-operand use).

// ---------------------------------------------------------------------------
// wswz: grid 3 x 256. Block b rewrites W[b] (fp32 [128][128]) into fragment
// layout bf16 (32KB). QSCALE folded into Wq.
// ---------------------------------------------------------------------------
__global__ __launch_bounds__(256) void wswz(const float* __restrict__ Wq,
                                            const float* __restrict__ Wk,
                                            const float* __restrict__ Wv,
                                            bf16* __restrict__ wf) {
    const float* __restrict__ W =
        (blockIdx.x == 0) ? Wq : (blockIdx.x == 1) ? Wk : Wv;
    const float s = (blockIdx.x == 0) ? QSCALE : 1.0f;
    bf16* __restrict__ out = wf + blockIdx.x * 16384;
    const int r = threadIdx.x >> 1;
    const int c0 = (threadIdx.x & 1) * 64;
#pragma unroll
    for (int g = 0; g < 8; g++) {
        const int h = c0 + g * 8;
        f32x4 a = *(const f32x4*)(W + r * D + h);
        f32x4 b = *(const f32x4*)(W + r * D + h + 4);
        bf16x8 v;
        v[0] = (bf16)(a[0] * s); v[1] = (bf16)(a[1] * s);
        v[2] = (bf16)(a[2] * s); v[3] = (bf16)(a[3] * s);
        v[4] = (bf16)(b[0] * s); v[5] = (bf16)(b[1] * s);
        v[6] = (bf16)(b[2] * s); v[7] = (bf16)(b[3] * s);
        const int frag = (r >> 4) * 4 + (h >> 5);
        const int ln = ((h & 31) >> 3) * 16 + (r & 15);
        *(bf16x8*)&out[(frag * 64 + ln) * 8] = v;
    }
}

// ---------------------------------------------------------------------------
// proj: grid 1024 x 256, barrier-free. Block = 16 tokens; wave 0 -> Q,
// 1 -> K, 2 -> V o0..63, 3 -> V o64..127. W-fragments are coalesced 1KB
// loads (L2-hot, reused by all blocks). Private-LDS transpose, coalesced
// dwordx4 stores.
// ---------------------------------------------------------------------------
__global__ __launch_bounds__(256) void proj(const float* __restrict__ x,
                                            const bf16* __restrict__ wf,
                                            bf16* __restrict__ qf,
                                            bf16* __restrict__ kf,
                                            bf16* __restrict__ vf) {
    __shared__ __attribute__((aligned(16))) bf16 Scr[4][2560];

    const int lane = threadIdx.x & 63;
    const int w = threadIdx.x >> 6;
    const int l16 = lane & 15;
    const int quad = lane >> 4;
    const int tile = blockIdx.x;
    const int tok0 = tile * 16;

    bf16x8 xa[4];
#pragma unroll
    for (int ks = 0; ks < 4; ks++)
        xa[ks] = ld8_f32_bf16(x + (tok0 + l16) * D + ks * 32 + quad * 8);

    if (w < 2) {
        const bf16* __restrict__ wp = wf + w * 16384;
        bf16* __restrict__ outp = (w == 0) ? qf : kf;
        bf16* __restrict__ T = Scr[w];  // [16][136]
#pragma unroll
        for (int nt = 0; nt < 8; nt++) {
            f32x4 acc = {0.f, 0.f, 0.f, 0.f};
#pragma unroll
            for (int ks = 0; ks < 4; ks++) {
                bf16x8 bw = *(const bf16x8*)(wp + ((nt * 4 + ks) * 64 + lane) * 8);
                acc = MFMA16(xa[ks], bw, acc);
            }
#pragma unroll
            for (int rg = 0; rg < 4; rg++)
                T[(quad * 4 + rg) * 136 + nt * 16 + l16] = (bf16)acc[rg];
        }
#pragma unroll
        for (int ks = 0; ks < 4; ks++) {
            bf16x8 frag = *(const bf16x8*)&T[l16 * 136 + ks * 32 + quad * 8];
            *(bf16x8*)(outp + (((size_t)tile * 4 + ks) * 64 + lane) * 8) = frag;
        }
    } else {
        const bf16* __restrict__ wp = wf + 2 * 16384;
        const int mt0 = (w - 2) * 4;
        bf16* __restrict__ T = Scr[w];  // [64][24]
#pragma unroll
        for (int mi = 0; mi < 4; mi++) {
            const int mt = mt0 + mi;
            f32x4 acc = {0.f, 0.f, 0.f, 0.f};
#pragma unroll
            for (int ks = 0; ks < 4; ks++) {
                bf16x8 aw = *(const bf16x8*)(wp + ((mt * 4 + ks) * 64 + lane) * 8);
                acc = MFMA16(aw, xa[ks], acc);
            }
#pragma unroll
            for (int rg = 0; rg < 4; rg++)
                T[(mi * 16 + quad * 4 + rg) * 24 + l16] = (bf16)acc[rg];
        }
        const int batch = tok0 >> 12;
        const int tokb = tok0 & (N - 1);
        const size_t vg = batch * 128 + (tokb >> 5);
        const int q0v = (tokb & 31) >> 3;  // 0 or 2
        const int dq = (lane >> 4) & 1;
        const int o15 = lane & 15;
#pragma unroll
        for (int s = 0; s < 2; s++) {
            const int otl = s * 2 + (lane >> 5);
            bf16x8 frag = *(const bf16x8*)&T[(otl * 16 + o15) * 24 + dq * 8];
            *(bf16x8*)(vf + ((vg * 8 + mt0 + otl) * 64 + (q0v + dq) * 16 + o15) * 8) =
                frag;
        }
    }
}

// ---------------------------------------------------------------------------
// flash: grid 512 x 512. Block = 1 q-pair (32 rows); 8 waves = 8 key-splits
// of 512 keys (8 iters of 64). r6's spill-free inner loop (2 qt/wave,
// oacc 72 regs, VGPR=128 via waves_per_eu(4,4)). S=8 combined in-block by a
// 2-level LDS tree; y written directly. 4096 waves = 4/SIMD.
// ---------------------------------------------------------------------------
__global__ __launch_bounds__(512) __attribute__((amdgpu_waves_per_eu(4, 4)))
void flash(const bf16* __restrict__ qf,
           const bf16* __restrict__ kf,
           const bf16* __restrict__ vf,
           float* __restrict__ out) {
    // main: Ps 8 waves x [2 qt][16][72] bf16 = 36864B
    // combine (aliased): Rs[6][16][148] f32 = 56832B
    __shared__ __attribute__((aligned(16))) unsigned char smem[56832];

    const int lane = threadIdx.x & 63;
    const int w = threadIdx.x >> 6;  // 0..7 = key split
    const int l16 = lane & 15;
    const int quad = lane >> 4;

    // XCD swizzle: bid%8 = XCD; 2 XCDs per batch -> K/V (2MB) L2-resident.
    const int lo = blockIdx.x & 7;
    const int hi = blockIdx.x >> 3;            // 0..63
    const int batch = lo >> 1;
    const int qpair = hi * 2 + (lo & 1);       // 0..127
    const int qtg0 = batch * 256 + qpair * 2;  // global q-tile of tile 0

    bf16* __restrict__ Psw = (bf16*)smem + w * 2304;  // [2 qt][16][72]

    bf16x8 aq[2][4];
#pragma unroll
    for (int qt = 0; qt < 2; qt++)
#pragma unroll
        for (int ks = 0; ks < 4; ks++)
            aq[qt][ks] =
                *(const bf16x8*)(qf + (((size_t)(qtg0 + qt) * 4 + ks) * 64 + lane) * 8);

    f32x4 oacc[2][9];
#pragma unroll
    for (int qt = 0; qt < 2; qt++)
#pragma unroll
        for (int i = 0; i < 9; i++) oacc[qt][i] = (f32x4){0.f, 0.f, 0.f, 0.f};

    bf16x8 vone;
#pragma unroll
    for (int j = 0; j < 8; j++) vone[j] = (bf16)1.0f;

    const int kb0 = w * 512;  // key base within batch

#pragma unroll 1
    for (int it = 0; it < 8; it++) {
        const int kb = kb0 + it * 64;
        const int kt = batch * 256 + (kb >> 4);

        // ---- K batch ----
        bf16x8 bk[4][4];
#pragma unroll
        for (int nt = 0; nt < 4; nt++)
#pragma unroll
            for (int ks = 0; ks < 4; ks++)
                bk[nt][ks] = *(const bf16x8*)(kf +
                    (((size_t)(kt + nt) * 4 + ks) * 64 + lane) * 8);

        // ---- S = q''.k^T (both tiles share bk) ----
        f32x4 sv[2][4];
#pragma unroll
        for (int qt = 0; qt < 2; qt++)
#pragma unroll
            for (int nt = 0; nt < 4; nt++) sv[qt][nt] = (f32x4){0.f, 0.f, 0.f, 0.f};
#pragma unroll
        for (int ks = 0; ks < 4; ks++)
#pragma unroll
            for (int nt = 0; nt < 4; nt++) {
                sv[0][nt] = MFMA16(aq[0][ks], bk[nt][ks], sv[0][nt]);
                sv[1][nt] = MFMA16(aq[1][ks], bk[nt][ks], sv[1][nt]);
            }
        __builtin_amdgcn_sched_barrier(0);

        // ---- V batch 1 (ot 0..3); latency hides under exp2 ----
        const size_t vg = batch * 128 + (kb >> 5);
        bf16x8 bv1[4][2];
#pragma unroll
        for (int ot = 0; ot < 4; ot++)
#pragma unroll
            for (int g2 = 0; g2 < 2; g2++)
                bv1[ot][g2] =
                    *(const bf16x8*)(vf + (((vg + g2) * 8 + ot) * 64 + lane) * 8);
        __builtin_amdgcn_sched_barrier(0);

        // ---- P = exp2(S) -> wave-private LDS strips ----
#pragma unroll
        for (int qt = 0; qt < 2; qt++)
#pragma unroll
            for (int nt = 0; nt < 4; nt++)
#pragma unroll
                for (int rg = 0; rg < 4; rg++)
                    Psw[qt * 1152 + (quad * 4 + rg) * 72 + nt * 16 + l16] =
                        (bf16)EXP2F(sv[qt][nt][rg]);
        __builtin_amdgcn_sched_barrier(0);

        // ---- V batch 2 (ot 4..7) ----
        bf16x8 bv2[4][2];
#pragma unroll
        for (int ot = 0; ot < 4; ot++)
#pragma unroll
            for (int g2 = 0; g2 < 2; g2++)
                bv2[ot][g2] =
                    *(const bf16x8*)(vf + (((vg + g2) * 8 + ot + 4) * 64 + lane) * 8);
        __builtin_amdgcn_sched_barrier(0);

        // ---- P back as A-fragments ----
        bf16x8 ap[2][2];
#pragma unroll
        for (int qt = 0; qt < 2; qt++)
#pragma unroll
            for (int g2 = 0; g2 < 2; g2++)
                ap[qt][g2] =
                    *(const bf16x8*)&Psw[qt * 1152 + l16 * 72 + g2 * 32 + quad * 8];

        // ---- O += P.V ----
#pragma unroll
        for (int ot = 0; ot < 4; ot++)
#pragma unroll
            for (int g2 = 0; g2 < 2; g2++) {
                oacc[0][ot] = MFMA16(ap[0][g2], bv1[ot][g2], oacc[0][ot]);
                oacc[1][ot] = MFMA16(ap[1][g2], bv1[ot][g2], oacc[1][ot]);
            }
#pragma unroll
        for (int ot = 0; ot < 4; ot++)
#pragma unroll
            for (int g2 = 0; g2 < 2; g2++) {
                oacc[0][ot + 4] = MFMA16(ap[0][g2], bv2[ot][g2], oacc[0][ot + 4]);
                oacc[1][ot + 4] = MFMA16(ap[1][g2], bv2[ot][g2], oacc[1][ot + 4]);
            }
#pragma unroll
        for (int qt = 0; qt < 2; qt++)
#pragma unroll
            for (int g2 = 0; g2 < 2; g2++)
                oacc[qt][8] = MFMA16(ap[qt][g2], vone, oacc[qt][8]);
    }

    // ---- in-block tree combine of 8 splits (per qt, fully unrolled) ----
    __syncthreads();  // all waves done with Ps before Rs overwrites
    float* __restrict__ Rs = (float*)smem;  // [6][16][148]
#pragma unroll
    for (int qt = 0; qt < 2; qt++) {
        if (qt) __syncthreads();
        // stage A: waves {1,2,3,5,6,7} publish
        if (w != 0 && w != 4) {
            const int slot = (w < 4) ? (w - 1) : (w - 2);  // 0..5
            float* __restrict__ dst = Rs + slot * (16 * 148);
#pragma unroll
            for (int t = 0; t < 9; t++)
#pragma unroll
                for (int rg = 0; rg < 4; rg++)
                    dst[(quad * 4 + rg) * 148 + t * 16 + l16] = oacc[qt][t][rg];
        }
        __syncthreads();
        // stage B: w0 sums slots 0..2, w4 sums slots 3..5
        if (w == 0 || w == 4) {
            const int base = (w == 0) ? 0 : 3;
#pragma unroll
            for (int sIdx = 0; sIdx < 3; sIdx++) {
                const float* __restrict__ src = Rs + (base + sIdx) * (16 * 148);
#pragma unroll
                for (int t = 0; t < 9; t++)
#pragma unroll
                    for (int rg = 0; rg < 4; rg++)
                        oacc[qt][t][rg] += src[(quad * 4 + rg) * 148 + t * 16 + l16];
            }
        }
        __syncthreads();
        // stage C: w4 publishes its half-sum to slot 0
        if (w == 4) {
            float* __restrict__ dst = Rs;
#pragma unroll
            for (int t = 0; t < 9; t++)
#pragma unroll
                for (int rg = 0; rg < 4; rg++)
                    dst[(quad * 4 + rg) * 148 + t * 16 + l16] = oacc[qt][t][rg];
        }
        __syncthreads();
        // final: w0 adds, normalizes, stores y
        if (w == 0) {
#pragma unroll
            for (int t = 0; t < 9; t++)
#pragma unroll
                for (int rg = 0; rg < 4; rg++)
                    oacc[qt][t][rg] += Rs[(quad * 4 + rg) * 148 + t * 16 + l16];
#pragma unroll
            for (int rg = 0; rg < 4; rg++) {
                const float rl = 1.0f / oacc[qt][8][rg];
                float* __restrict__ yrow =
                    out + (((size_t)(qtg0 + qt)) * 16 + quad * 4 + rg) * D;
#pragma unroll
                for (int t = 0; t < 8; t++)
                    yrow[t * 16 + l16] = oacc[qt][t][rg] * rl;
            }
        }
    }
}

// ---------------------------------------------------------------------------
extern "C" void kernel_launch(void* const* d_in, const int* in_sizes, int n_in,
                              void* d_out, int out_size, void* d_ws, size_t ws_size,
                              hipStream_t stream) {
    const float* x = (const float*)d_in[0];
    const float* Wq = (const float*)d_in[1];
    const float* Wk = (const float*)d_in[2];
    const float* Wv = (const float*)d_in[3];
    float* y = (float*)d_out;

    // ws: qf 4MB | kf 4MB | vf 4MB | wf 96KB
    bf16* qf = (bf16*)d_ws;
    bf16* kf = qf + (size_t)ROWS * D;
    bf16* vf = kf + (size_t)ROWS * D;
    bf16* wf = vf + (size_t)ROWS * D;

    wswz<<<3, 256, 0, stream>>>(Wq, Wk, Wv, wf);
    proj<<<1024, 256, 0, stream>>>(x, wf, qf, kf, vf);
    flash<<<512, 512, 0, stream>>>(qf, kf, vf, y);
}

// Round 11
// 144.555 us; speedup vs baseline: 1.5691x; 1.5691x over previous
//
#include <hip/hip_runtime.h>

// ---------------------------------------------------------------------------
// Attention: y = softmax( (xWq^T)(xWk^T)^T / sqrt(128) ) (xWv^T)
// B=4, N=4096, H=OUT=128. fp32 I/O, bf16 MFMA compute.
//
// R11: cooperative fusion (r10) never launched -> back to plain launches.
// Attack flash's structural L2 floor instead: r6's 51.7us streamed 32KB of
// K/V per WAVE-iter (1.05GB L2). Now block = 128 q-rows (4 waves x the
// proven spill-free 2qt/wave loop) and the 64-key K/V tile is staged ONCE
// per block-iter into LDS (two contiguous 16KB copies) and shared by all 4
// waves -> ingest 268MB. Key split S=4 across blocks (grid 512 = 2/CU),
// fp32 partials (coalesced rows) + tiny norm kernel.
// proj: wswz dropped; W fragments loaded directly from fp32 global
// (r0-pattern, L2-hot), per-wave LDS transpose stores (r9 pattern).
// ---------------------------------------------------------------------------

typedef __bf16 bf16;
typedef __attribute__((ext_vector_type(8))) __bf16 bf16x8;
typedef __attribute__((ext_vector_type(4))) float f32x4;

#define MFMA16(a, b, c) __builtin_amdgcn_mfma_f32_16x16x32_bf16(a, b, c, 0, 0, 0)

#if __has_builtin(__builtin_amdgcn_exp2f)
#define EXP2F(x) __builtin_amdgcn_exp2f(x)
#else
#define EXP2F(x) exp2f(x)
#endif

static constexpr int BATCH = 4;
static constexpr int N = 4096;
static constexpr int D = 128;
static constexpr int ROWS = BATCH * N;  // 16384
static constexpr int SPLITS = 4;
// fold 1/sqrt(128) and log2(e) into q so softmax is raw exp2
static constexpr float QSCALE = 0.088388347648318447f * 1.4426950408889634f;

__device__ inline bf16x8 ld8_f32_bf16(const float* __restrict__ p) {
    f32x4 a = *(const f32x4*)p;
    f32x4 b = *(const f32x4*)(p + 4);
    bf16x8 r;
    r[0] = (bf16)a[0]; r[1] = (bf16)a[1]; r[2] = (bf16)a[2]; r[3] = (bf16)a[3];
    r[4] = (bf16)b[0]; r[5] = (bf16)b[1]; r[6] = (bf16)b[2]; r[7] = (bf16)b[3];
    return r;
}

// Fragment layouts (16x16x32 bf16; lane = quad*16 + l16):
//  qf/kf: (tile,row,d) -> ((tile*4 + (d>>5))*64 + ((d&31)>>3)*16 + row)*8 + (d&7)
//  vf:    (o,key)      -> ((vg*8 + (o>>4))*64 + ((key&31)>>3)*16 + (o&15))*8 + (key&7)
//         with vg = batch*128 + (key_in_batch>>5)

// ---------------------------------------------------------------------------
// proj: grid 1024 x 256, barrier-free. Block = 16 tokens; wave 0 -> Q,
// 1 -> K, 2/3 -> V o-halves. W fragments loaded directly from fp32 rows
// (B/A-frag lane layout == 8 contiguous floats of one W row). Per-wave LDS
// transpose, coalesced dwordx4 stores.
// ---------------------------------------------------------------------------
__global__ __launch_bounds__(256) void proj(const float* __restrict__ x,
                                            const float* __restrict__ Wq,
                                            const float* __restrict__ Wk,
                                            const float* __restrict__ Wv,
                                            bf16* __restrict__ qf,
                                            bf16* __restrict__ kf,
                                            bf16* __restrict__ vf) {
    __shared__ __attribute__((aligned(16))) bf16 Scr[4][2560];

    const int lane = threadIdx.x & 63;
    const int w = threadIdx.x >> 6;
    const int l16 = lane & 15;
    const int quad = lane >> 4;
    const int tile = blockIdx.x;
    const int tok0 = tile * 16;

    bf16x8 xa[4];
#pragma unroll
    for (int ks = 0; ks < 4; ks++)
        xa[ks] = ld8_f32_bf16(x + (tok0 + l16) * D + ks * 32 + quad * 8);

    if (w < 2) {
        const float* __restrict__ W = (w == 0) ? Wq : Wk;
        bf16* __restrict__ outp = (w == 0) ? qf : kf;
        const float scale = (w == 0) ? QSCALE : 1.0f;
        bf16* __restrict__ T = Scr[w];  // [16][136]
#pragma unroll
        for (int nt = 0; nt < 8; nt++) {
            f32x4 acc = {0.f, 0.f, 0.f, 0.f};
#pragma unroll
            for (int ks = 0; ks < 4; ks++) {
                bf16x8 bw = ld8_f32_bf16(W + (nt * 16 + l16) * D + ks * 32 + quad * 8);
                acc = MFMA16(xa[ks], bw, acc);
            }
#pragma unroll
            for (int rg = 0; rg < 4; rg++)
                T[(quad * 4 + rg) * 136 + nt * 16 + l16] = (bf16)(acc[rg] * scale);
        }
#pragma unroll
        for (int ks = 0; ks < 4; ks++) {
            bf16x8 frag = *(const bf16x8*)&T[l16 * 136 + ks * 32 + quad * 8];
            *(bf16x8*)(outp + (((size_t)tile * 4 + ks) * 64 + lane) * 8) = frag;
        }
    } else {
        const int mt0 = (w - 2) * 4;
        bf16* __restrict__ T = Scr[w];  // [64][24]
#pragma unroll
        for (int mi = 0; mi < 4; mi++) {
            const int mt = mt0 + mi;
            f32x4 acc = {0.f, 0.f, 0.f, 0.f};
#pragma unroll
            for (int ks = 0; ks < 4; ks++) {
                bf16x8 aw = ld8_f32_bf16(Wv + (mt * 16 + l16) * D + ks * 32 + quad * 8);
                acc = MFMA16(aw, xa[ks], acc);
            }
#pragma unroll
            for (int rg = 0; rg < 4; rg++)
                T[(mi * 16 + quad * 4 + rg) * 24 + l16] = (bf16)acc[rg];
        }
        const int batch = tok0 >> 12;
        const int tokb = tok0 & (N - 1);
        const size_t vg = batch * 128 + (tokb >> 5);
        const int q0v = (tokb & 31) >> 3;  // 0 or 2
        const int dq = (lane >> 4) & 1;
        const int o15 = lane & 15;
#pragma unroll
        for (int s = 0; s < 2; s++) {
            const int otl = s * 2 + (lane >> 5);
            bf16x8 frag = *(const bf16x8*)&T[(otl * 16 + o15) * 24 + dq * 8];
            *(bf16x8*)(vf + ((vg * 8 + mt0 + otl) * 64 + (q0v + dq) * 16 + o15) * 8) =
                frag;
        }
    }
}

// ---------------------------------------------------------------------------
// flash: grid 512 x 256. Block = (batch, qslice g: 128 rows, split s: 1024
// keys). Wave w owns q-tiles {g*8+2w, +1} (r6's spill-free 2qt loop). Per
// iter the 64-key K/V tile (32KB) is staged into LDS by all threads and
// consumed by all 4 waves. Partials (fp32 O + l) to pbuf; norm finishes.
// ---------------------------------------------------------------------------
__global__ __launch_bounds__(256) __attribute__((amdgpu_waves_per_eu(2, 2)))
void flash(const bf16* __restrict__ qf,
           const bf16* __restrict__ kf,
           const bf16* __restrict__ vf,
           float* __restrict__ pbuf,
           float* __restrict__ lbuf) {
    // Ks 16KB @0 | Vs 16KB @16384 | Ps 4 waves x 4608B @32768  -> 51200B
    __shared__ __attribute__((aligned(16))) unsigned char smem[51200];

    const int lane = threadIdx.x & 63;
    const int w = threadIdx.x >> 6;  // 0..3
    const int l16 = lane & 15;
    const int quad = lane >> 4;
    const int tid = threadIdx.x;

    // XCD swizzle: bid%8 = XCD; 2 XCDs per batch -> K/V slice L2-resident.
    const int lo = blockIdx.x & 7;
    const int batch = lo >> 1;
    const int t = (blockIdx.x >> 3) * 2 + (lo & 1);  // 0..127
    const int g = t >> 2;                            // q-slice 0..31
    const int s = t & 3;                             // key split 0..3
    const int qtg = batch * 256 + g * 8 + w * 2;     // this wave's q-tile 0

    bf16* __restrict__ Ks = (bf16*)smem;
    bf16* __restrict__ Vs = (bf16*)(smem + 16384);
    bf16* __restrict__ Psw = (bf16*)(smem + 32768) + w * 2304;  // [2qt][16][72]

    bf16x8 aq[2][4];
#pragma unroll
    for (int qt = 0; qt < 2; qt++)
#pragma unroll
        for (int ks = 0; ks < 4; ks++)
            aq[qt][ks] =
                *(const bf16x8*)(qf + (((size_t)(qtg + qt) * 4 + ks) * 64 + lane) * 8);

    f32x4 oacc[2][9];
#pragma unroll
    for (int qt = 0; qt < 2; qt++)
#pragma unroll
        for (int i = 0; i < 9; i++) oacc[qt][i] = (f32x4){0.f, 0.f, 0.f, 0.f};

    bf16x8 vone;
#pragma unroll
    for (int j = 0; j < 8; j++) vone[j] = (bf16)1.0f;

#pragma unroll 1
    for (int it = 0; it < 16; it++) {
        const int kb = s * 1024 + it * 64;            // key base within batch
        const size_t kt = batch * 256 + (kb >> 4);    // global k-tile
        const size_t vg = batch * 128 + (kb >> 5);    // global v-group

        // ---- stage K (16KB) + V (16KB) tiles into LDS, all 256 threads ----
        __syncthreads();  // prior iter's LDS reads complete
        {
            const bf16x8* __restrict__ sK = (const bf16x8*)kf + kt * 256;
            bf16x8* __restrict__ dK = (bf16x8*)Ks;
#pragma unroll
            for (int j = 0; j < 4; j++) dK[tid + j * 256] = sK[tid + j * 256];
            const bf16x8* __restrict__ sV = (const bf16x8*)vf + vg * 512;
            bf16x8* __restrict__ dV = (bf16x8*)Vs;
#pragma unroll
            for (int j = 0; j < 4; j++) dV[tid + j * 256] = sV[tid + j * 256];
        }
        __syncthreads();

        // ---- K fragments from LDS ----
        bf16x8 bk[4][4];
#pragma unroll
        for (int nt = 0; nt < 4; nt++)
#pragma unroll
            for (int ks = 0; ks < 4; ks++)
                bk[nt][ks] = *(const bf16x8*)&Ks[((nt * 4 + ks) * 64 + lane) * 8];

        // ---- S = q''.k^T (both q-tiles share bk) ----
        f32x4 sv[2][4];
#pragma unroll
        for (int qt = 0; qt < 2; qt++)
#pragma unroll
            for (int nt = 0; nt < 4; nt++) sv[qt][nt] = (f32x4){0.f, 0.f, 0.f, 0.f};
#pragma unroll
        for (int ks = 0; ks < 4; ks++)
#pragma unroll
            for (int nt = 0; nt < 4; nt++) {
                sv[0][nt] = MFMA16(aq[0][ks], bk[nt][ks], sv[0][nt]);
                sv[1][nt] = MFMA16(aq[1][ks], bk[nt][ks], sv[1][nt]);
            }

        // ---- P = exp2(S) -> wave-private LDS strips ----
#pragma unroll
        for (int qt = 0; qt < 2; qt++)
#pragma unroll
            for (int nt = 0; nt < 4; nt++)
#pragma unroll
                for (int rg = 0; rg < 4; rg++)
                    Psw[qt * 1152 + (quad * 4 + rg) * 72 + nt * 16 + l16] =
                        (bf16)EXP2F(sv[qt][nt][rg]);

        // ---- P back as A-fragments ----
        bf16x8 ap[2][2];
#pragma unroll
        for (int qt = 0; qt < 2; qt++)
#pragma unroll
            for (int g2 = 0; g2 < 2; g2++)
                ap[qt][g2] =
                    *(const bf16x8*)&Psw[qt * 1152 + l16 * 72 + g2 * 32 + quad * 8];

        // ---- O += P.V from LDS (V fragments shared by both q-tiles) ----
#pragma unroll
        for (int ot = 0; ot < 8; ot++) {
            bf16x8 bv0 = *(const bf16x8*)&Vs[((0 * 8 + ot) * 64 + lane) * 8];
            bf16x8 bv1 = *(const bf16x8*)&Vs[((1 * 8 + ot) * 64 + lane) * 8];
            oacc[0][ot] = MFMA16(ap[0][0], bv0, oacc[0][ot]);
            oacc[0][ot] = MFMA16(ap[0][1], bv1, oacc[0][ot]);
            oacc[1][ot] = MFMA16(ap[1][0], bv0, oacc[1][ot]);
            oacc[1][ot] = MFMA16(ap[1][1], bv1, oacc[1][ot]);
        }
#pragma unroll
        for (int qt = 0; qt < 2; qt++) {
            oacc[qt][8] = MFMA16(ap[qt][0], vone, oacc[qt][8]);
            oacc[qt][8] = MFMA16(ap[qt][1], vone, oacc[qt][8]);
        }
    }

    // ---- write fp32 partials (coalesced full rows) ----
#pragma unroll
    for (int qt = 0; qt < 2; qt++) {
        const int tileg = qtg + qt;
#pragma unroll
        for (int rg = 0; rg < 4; rg++) {
            const int row = tileg * 16 + quad * 4 + rg;
            float* __restrict__ prow = pbuf + ((size_t)s * ROWS + row) * D;
#pragma unroll
            for (int t8 = 0; t8 < 8; t8++)
                prow[t8 * 16 + l16] = oacc[qt][t8][rg];
        }
        if (l16 == 0) {
#pragma unroll
            for (int rg = 0; rg < 4; rg++)
                lbuf[s * ROWS + tileg * 16 + quad * 4 + rg] = oacc[qt][8][rg];
        }
    }
}

// ---------------------------------------------------------------------------
// norm: y = (sum_s O_s) / (sum_s l_s). grid 512 x 256; thread = 16-col seg.
// ---------------------------------------------------------------------------
__global__ __launch_bounds__(256) void norm(const float* __restrict__ pbuf,
                                            const float* __restrict__ lbuf,
                                            float* __restrict__ out) {
    const int idx = blockIdx.x * 256 + threadIdx.x;  // 0..131071
    const int row = idx >> 3;
    const int seg = (idx & 7) * 16;

    float L = 0.f;
#pragma unroll
    for (int s = 0; s < SPLITS; s++) L += lbuf[s * ROWS + row];
    const float rl = 1.0f / L;

    float acc[16];
#pragma unroll
    for (int i = 0; i < 16; i++) acc[i] = 0.f;
#pragma unroll
    for (int s = 0; s < SPLITS; s++) {
        const float* __restrict__ p = pbuf + ((size_t)s * ROWS + row) * D + seg;
#pragma unroll
        for (int k = 0; k < 4; k++) {
            f32x4 v = *(const f32x4*)(p + k * 4);
            acc[k * 4 + 0] += v[0];
            acc[k * 4 + 1] += v[1];
            acc[k * 4 + 2] += v[2];
            acc[k * 4 + 3] += v[3];
        }
    }
    float* __restrict__ o = out + (size_t)row * D + seg;
#pragma unroll
    for (int k = 0; k < 4; k++) {
        f32x4 r = {acc[k * 4 + 0] * rl, acc[k * 4 + 1] * rl, acc[k * 4 + 2] * rl,
                   acc[k * 4 + 3] * rl};
        *(f32x4*)(o + k * 4) = r;
    }
}

// ---------------------------------------------------------------------------
extern "C" void kernel_launch(void* const* d_in, const int* in_sizes, int n_in,
                              void* d_out, int out_size, void* d_ws, size_t ws_size,
                              hipStream_t stream) {
    const float* x = (const float*)d_in[0];
    const float* Wq = (const float*)d_in[1];
    const float* Wk = (const float*)d_in[2];
    const float* Wv = (const float*)d_in[3];
    float* y = (float*)d_out;

    // ws: qf 4MB | kf 4MB | vf 4MB | pbuf 32MB | lbuf 256KB
    bf16* qf = (bf16*)d_ws;
    bf16* kf = qf + (size_t)ROWS * D;
    bf16* vf = kf + (size_t)ROWS * D;
    float* pbuf = (float*)(vf + (size_t)ROWS * D);
    float* lbuf = pbuf + (size_t)SPLITS * ROWS * D;

    proj<<<1024, 256, 0, stream>>>(x, Wq, Wk, Wv, qf, kf, vf);
    flash<<<512, 256, 0, stream>>>(qf, kf, vf, pbuf, lbuf);
    norm<<<512, 256, 0, stream>>>(pbuf, lbuf, y);
}